// Round 4
// baseline (655.987 us; speedup 1.0000x reference)
//
#include <hip/hip_runtime.h>

// ---------------------------------------------------------------------------
// HardwareOptimizedQuantumLLM  (B=4, S=1024, D=512, V=8192, SCALES={1,2,4,8,16}, WIN=8)
//
// R4: dispatch count 24->16 (k_pre = tanh+cmean; k_coh = msc+sem fused band
// pass; k_wbig = prep|wcf|wsmall block-switched; k_packfin = pack+wfin).
// k_dots staging conflict fix: DP 76->77 (odd stride), b32 writes.
// ---------------------------------------------------------------------------

#define DEV __device__ __forceinline__
typedef unsigned short u16;
typedef __bf16 bf16x8 __attribute__((ext_vector_type(8)));
typedef float f32x4 __attribute__((ext_vector_type(4)));

static constexpr int S = 1024;
static constexpr int D = 512;
static constexpr int KCAT = 1056;   // 512 ctx + 512 lc + 5 msc + 1 sem + 1 const + 25 pad

DEV u16 f2bf(float f) {            // fp32 -> bf16 (RNE)
  unsigned u = __float_as_uint(f);
  return (u16)((u + 0x7fffu + ((u >> 16) & 1u)) >> 16);
}
DEV float gelu(float x) { return 0.5f * x * (1.f + erff(x * 0.70710678118654752f)); }
DEV float wred(float v) {
#pragma unroll
  for (int off = 32; off; off >>= 1) v += __shfl_down(v, off, 64);
  return v;  // lane 0 holds the sum
}
DEV void bred2(float& a, float& b, float* sm, int tid) {  // 256-thread block reduce, 2 vals
  a = wred(a); b = wred(b);
  int w = tid >> 6;
  if ((tid & 63) == 0) { sm[w] = a; sm[w + 4] = b; }
  __syncthreads();
  a = sm[0] + sm[1] + sm[2] + sm[3];
  b = sm[4] + sm[5] + sm[6] + sm[7];
  __syncthreads();
}

// ---------------- pre: blocks 0..1023 tanh(emb); 1024..1055 cmean ----------------
__global__ __launch_bounds__(256) void k_pre(const float* __restrict__ emb,
                                             const float* __restrict__ mask,
                                             float* __restrict__ ph,
                                             float* __restrict__ cmacc) {
  int blk = blockIdx.x, tid = threadIdx.x;
  if (blk < 1024) {
    int idx = blk * 256 + tid;
#pragma unroll
    for (int r = 0; r < 2; ++r, idx += 262144) {
      float4 v = ((const float4*)emb)[idx];
      float4 o;
      o.x = tanhf(v.x); o.y = tanhf(v.y); o.z = tanhf(v.z); o.w = tanhf(v.w);
      ((float4*)ph)[idx] = o;
    }
  } else {
    int r = blk - 1024, b = r >> 3, chunk = r & 7;
    float a0 = 0.f, a1 = 0.f;
    for (int s = chunk * 128; s < chunk * 128 + 128; ++s) {
      float m = mask[b * S + s];
      const float* row = emb + (size_t)(b * S + s) * D;
      a0 += row[tid] * m; a1 += row[tid + 256] * m;
    }
    atomicAdd(cmacc + b * D + tid, a0);
    atomicAdd(cmacc + b * D + tid + 256, a1);
  }
}

// ---------------- banded tsim + norms, chunk-parallel band staging ----------------
// grid.x = B*16 (64-anchor groups), grid.y = 32 (256-float V chunks)
// LDS sT[c][r]: 256 x 77 fp32 (72 rows used; odd stride -> conflict-free writes).
static constexpr int DP = 77;
__global__ __launch_bounds__(256) void k_dots(const float* __restrict__ sim,
                                              const int* __restrict__ tok,
                                              float* __restrict__ dots_raw,
                                              float* __restrict__ normsq) {
  __shared__ float sT[256 * DP];
  __shared__ int stok[72];
  int bx = blockIdx.x, cy = blockIdx.y, tid = threadIdx.x;
  int b = bx >> 4, g0 = (bx & 15) * 64;
  int gidx = b * S + g0;
  if (tid < 72) {
    int p = g0 + tid;
    stok[tid] = (p < S) ? tok[b * S + p] : -1;
  }
  __syncthreads();
  int c = tid, cbase = cy * 256;
#pragma unroll 3
  for (int it = 0; it < 18; ++it) {
#pragma unroll
    for (int j = 0; j < 4; ++j) {
      int tk = stok[it * 4 + j];
      sT[c * DP + it * 4 + j] = (tk >= 0) ? sim[(size_t)tk * 8192 + cbase + c] : 0.f;
    }
  }
  __syncthreads();
  int wave = tid >> 6, lane = tid & 63;
  float acc[9] = {};
#pragma unroll 2
  for (int cc = 0; cc < 64; ++cc) {
    const float* row = &sT[(wave * 64 + cc) * DP];
    float va = row[lane];
    acc[8] += va * va;
#pragma unroll
    for (int o = 1; o <= 8; ++o) acc[o - 1] += va * row[lane + o];
  }
  __syncthreads();            // done reading sT; reuse as reduction buffer
  float* red = sT;            // [wave][9][64]
#pragma unroll
  for (int s = 0; s < 9; ++s) red[(wave * 9 + s) * 64 + lane] = acc[s];
  __syncthreads();
  for (int u = tid; u < 576; u += 256) {
    int s = u >> 6, a = u & 63;
    float v = red[s * 64 + a] + red[(9 + s) * 64 + a] +
              red[(18 + s) * 64 + a] + red[(27 + s) * 64 + a];
    if (s < 8) atomicAdd(&dots_raw[(size_t)(gidx + a) * 8 + s], v);
    else       atomicAdd(&normsq[gidx + a], v);
  }
}

// ---------------- fused msc + sem: one wave per (b,i), single band pass ----------------
__global__ __launch_bounds__(256) void k_coh(const float* __restrict__ ph,
                                             const float* __restrict__ dots_raw,
                                             const float* __restrict__ normsq,
                                             float* __restrict__ msc,
                                             float* __restrict__ semacc) {
  __shared__ float sw[4][17];
  int wave = threadIdx.x >> 6, lane = threadIdx.x & 63;
  int idx = blockIdx.x * 4 + wave, i = idx & 1023;
  if (lane < 17) {                       // swin coefficients from banded dots
    int o = lane - 8, j = i + o;
    float v = 0.f;
    if (j >= 0 && j < S) {
      if (o == 0) v = 1.f;
      else {
        float dr = (o > 0) ? dots_raw[(size_t)idx * 8 + o - 1]
                           : dots_raw[(size_t)(idx + o) * 8 + (-o - 1)];
        float ni = fmaxf(sqrtf(normsq[idx]), 1e-12f);
        float nj = fmaxf(sqrtf(normsq[idx + o]), 1e-12f);
        v = dr / (ni * nj);
      }
    }
    sw[wave][lane] = v;
  }
  __syncthreads();
  int jmax = (S - 1 - i < 15) ? (S - 1 - i) : 15;
  float a0 = 0.f, a1 = 0.f, a2 = 0.f, a3 = 0.f, a4 = 0.f, asem = 0.f;
  for (int it = 0; it < 8; ++it) {
    int d = lane + it * 64;
    float p[24];                          // rows i-8 .. i+15 (clamped loads)
#pragma unroll
    for (int t = 0; t < 24; ++t) {
      int o = t - 8, j = i + o;
      int oc = (j >= 0 && j < S) ? o : 0;
      p[t] = ph[(size_t)(idx + oc) * D + d];
    }
    // --- msc: prefix over forward window ---
    float sp = 0.f, sc = 0.f, ss = 0.f;
#pragma unroll
    for (int j = 0; j < 16; ++j) {
      float x = (j <= jmax) ? p[j + 8] : 0.f;
      sp += x; sc += __cosf(x); ss += __sinf(x);
      if (j == 0) a0 += __cosf(sp) * sc + __sinf(sp) * ss;
      else if (j == 1)  { float wm = sp * 0.5f;    a1 += __cosf(wm) * (sc * 0.5f)    + __sinf(wm) * (ss * 0.5f); }
      else if (j == 3)  { float wm = sp * 0.25f;   a2 += __cosf(wm) * (sc * 0.25f)   + __sinf(wm) * (ss * 0.25f); }
      else if (j == 7)  { float wm = sp * 0.125f;  a3 += __cosf(wm) * (sc * 0.125f)  + __sinf(wm) * (ss * 0.125f); }
      else if (j == 15) { float wm = sp * 0.0625f; a4 += __cosf(wm) * (sc * 0.0625f) + __sinf(wm) * (ss * 0.0625f); }
    }
    // --- sem: +/-8 window, predicated ---
    float p0 = p[8];
#pragma unroll
    for (int oi = 0; oi < 17; ++oi) {
      int o = oi - 8, j = i + o;
      bool valid = (j >= 0) && (j < S);
      float sv = sw[wave][oi];
      asem += valid ? __cosf((p0 - p[oi]) * sv) : 0.f;
    }
  }
  a0 = wred(a0); a1 = wred(a1); a2 = wred(a2); a3 = wred(a3); a4 = wred(a4);
  asem = wred(asem);
  if (lane == 0) {
    float* o = msc + (size_t)idx * 5;
    o[0] = a0 * (1.f / 512.f);
    o[1] = (jmax >= 1)  ? a1 * (1.f / 512.f) : 0.f;
    o[2] = (jmax >= 3)  ? a2 * (1.f / 512.f) : 0.f;
    o[3] = (jmax >= 7)  ? a3 * (1.f / 512.f) : 0.f;
    o[4] = (jmax >= 15) ? a4 * (1.f / 512.f) : 0.f;
    atomicAdd(semacc + i, asem);
  }
}

// ---------------- weight stage A (block-switched): prep | wcf | wsmall ----------------
// blocks 0..255: transpose W_e0/1/2 + Wf4 -> bf16 [n][k]
// blocks 256..511: ctx_acc[k][n] += W_ctx[k][j]*Wf3[j][n] (j-split atomics)
// blocks 512..575: sm_acc[7][512] partial folds (j-split atomics)
__global__ __launch_bounds__(256) void k_wbig(const float* __restrict__ W0,
    const float* __restrict__ W1, const float* __restrict__ W2,
    const float* __restrict__ Wf, const float* __restrict__ wctx,
    const float* __restrict__ Wsc, const float* __restrict__ Wsm,
    const float* __restrict__ bsc, const float* __restrict__ bsm,
    const float* __restrict__ bcx,
    u16* __restrict__ T0, u16* __restrict__ T1, u16* __restrict__ T2,
    u16* __restrict__ wcatT, float* __restrict__ ctx_acc,
    float* __restrict__ sm_acc) {
  __shared__ float tile[64][65];
  int blk = blockIdx.x, tid = threadIdx.x;
  if (blk < 256) {
    int z = blk >> 6, rem = blk & 63;
    const float* src = z == 0 ? W0 : z == 1 ? W1 : z == 2 ? W2 : Wf + (size_t)1536 * 512;
    int r0 = (rem >> 3) * 64, c0 = (rem & 7) * 64;
    int tr = tid >> 6, tc = tid & 63;
#pragma unroll 4
    for (int i = 0; i < 16; ++i)
      tile[tr + i * 4][tc] = src[(size_t)(r0 + tr + i * 4) * 512 + c0 + tc];
    __syncthreads();
#pragma unroll 4
    for (int i = 0; i < 16; ++i) {
      int n = c0 + tr + i * 4, k = r0 + tc;
      u16 v = f2bf(tile[tc][tr + i * 4]);
      if (z == 3) wcatT[(size_t)n * KCAT + 512 + k] = v;
      else (z == 0 ? T0 : z == 1 ? T1 : T2)[(size_t)n * 512 + k] = v;
    }
  } else if (blk < 512) {
    int rem = blk - 256;
    int n = (rem & 1) * 256 + tid;
    int kbase = ((rem & 63) >> 1) * 16;
    int j0 = (rem >> 6) * 128;
    float acc[16] = {};
    for (int j = j0; j < j0 + 128; ++j) {
      float wf3 = Wf[(size_t)(1024 + j) * 512 + n];
#pragma unroll
      for (int kk = 0; kk < 16; ++kk) acc[kk] += wctx[(size_t)(kbase + kk) * 512 + j] * wf3;
    }
#pragma unroll
    for (int kk = 0; kk < 16; ++kk)
      atomicAdd(&ctx_acc[(size_t)(kbase + kk) * 512 + n], acc[kk]);
  } else {
    int rem = blk - 512;
    int n = (rem & 1) * 256 + tid;
    int j0 = (rem >> 1) * 16;
    float a0 = 0.f, a1 = 0.f, a2 = 0.f, a3 = 0.f, a4 = 0.f, au = 0.f, ac = 0.f;
    for (int j = j0; j < j0 + 16; ++j) {
      float wf1 = Wf[(size_t)j * 512 + n];
      float wf2 = Wf[(size_t)(512 + j) * 512 + n];
      float wf3 = Wf[(size_t)(1024 + j) * 512 + n];
      a0 += Wsc[j] * wf1; a1 += Wsc[512 + j] * wf1; a2 += Wsc[1024 + j] * wf1;
      a3 += Wsc[1536 + j] * wf1; a4 += Wsc[2048 + j] * wf1;
      au += Wsm[j] * wf2;
      ac += bsc[j] * wf1 + bsm[j] * wf2 + bcx[j] * wf3;
    }
    atomicAdd(&sm_acc[0 * 512 + n], a0);
    atomicAdd(&sm_acc[1 * 512 + n], a1);
    atomicAdd(&sm_acc[2 * 512 + n], a2);
    atomicAdd(&sm_acc[3 * 512 + n], a3);
    atomicAdd(&sm_acc[4 * 512 + n], a4);
    atomicAdd(&sm_acc[5 * 512 + n], au);
    atomicAdd(&sm_acc[6 * 512 + n], ac);
  }
}

// ---------------- weight stage B: pack ctx_acc -> wcatT (blk<64) | finalize (blk>=64) ----
__global__ __launch_bounds__(256) void k_packfin(const float* __restrict__ ctx_acc,
    const float* __restrict__ sm_acc, const float* __restrict__ bfu,
    u16* __restrict__ wcatT) {
  __shared__ float tile[64][65];
  int blk = blockIdx.x, tid = threadIdx.x;
  if (blk < 64) {
    int r0 = (blk >> 3) * 64, c0 = (blk & 7) * 64;  // r=k, c=n
    int tr = tid >> 6, tc = tid & 63;
#pragma unroll 4
    for (int i = 0; i < 16; ++i)
      tile[tr + i * 4][tc] = ctx_acc[(size_t)(r0 + tr + i * 4) * 512 + c0 + tc];
    __syncthreads();
#pragma unroll 4
    for (int i = 0; i < 16; ++i)
      wcatT[(size_t)(c0 + tr + i * 4) * KCAT + r0 + tc] = f2bf(tile[tc][tr + i * 4]);
  } else {
    int n = (blk - 64) * 256 + tid;
    u16* row = wcatT + (size_t)n * KCAT;
#pragma unroll
    for (int s = 0; s < 6; ++s) row[1024 + s] = f2bf(sm_acc[s * 512 + n]);
    row[1030] = f2bf(sm_acc[6 * 512 + n] + bfu[n]);
    for (int k = 1031; k < KCAT; ++k) row[k] = 0;
  }
}

// ---------------- build Xcat (bf16): [cos(emb-cmean) | lc | msc | sem | 1 | 0] ----------------
__global__ __launch_bounds__(256) void k_xcat(const float* __restrict__ emb,
    const float* __restrict__ cmacc, const float* __restrict__ msc,
    const float* __restrict__ semacc, u16* __restrict__ xcat) {
  int idx = blockIdx.x, b = idx >> 10, i = idx & 1023, tid = threadIdx.x;
  const float* erow = emb + (size_t)idx * D;
  u16* orow = xcat + (size_t)idx * KCAT;
  for (int c = tid; c < KCAT; c += 256) {
    float v;
    if (c < 512) {
      v = __cosf(erow[c] - cmacc[b * D + c] * (1.f / 1024.f));
    } else if (c < 1024) {
      int d = c - 512;
      v = (i < S - 1) ? __cosf(erow[D + d] - erow[d]) : 0.f;
    } else if (c < 1029) {
      v = msc[(size_t)idx * 5 + (c - 1024)];
    } else if (c == 1029) {
      int cnt = ((i < 8) ? i : 8) + ((S - 1 - i < 8) ? (S - 1 - i) : 8) + 1;
      v = semacc[i] / (4.f * (float)cnt * 512.f);
    } else if (c == 1030) {
      v = 1.f;
    } else v = 0.f;
    orow[c] = f2bf(v);
  }
}

// ---------------- bf16 MFMA GEMM: C[M,512] = A[M,K] @ BT[512,K]^T + bias ----------------
__global__ __launch_bounds__(256) void k_gemm(const u16* __restrict__ A,
    const u16* __restrict__ BT, float* __restrict__ C,
    const float* __restrict__ bias, int K) {
  __shared__ __align__(16) u16 sA[64 * 40];
  __shared__ __align__(16) u16 sB[64 * 40];
  int tid = threadIdx.x, wave = tid >> 6, lane = tid & 63;
  int m0 = blockIdx.x * 64, n0 = blockIdx.y * 64;
  int lr = tid >> 2, lc = (tid & 3) * 8;
  int q8 = (lane >> 4) * 8, l15 = lane & 15;
  const u16* Ap = A + (size_t)(m0 + lr) * K + lc;
  const u16* Bp = BT + (size_t)(n0 + lr) * K + lc;
  f32x4 acc[4] = {};
  for (int k0 = 0; k0 < K; k0 += 32) {
    *(uint4*)&sA[lr * 40 + lc] = *(const uint4*)(Ap + k0);
    *(uint4*)&sB[lr * 40 + lc] = *(const uint4*)(Bp + k0);
    __syncthreads();
    bf16x8 af = *(const bf16x8*)&sA[(wave * 16 + l15) * 40 + q8];
#pragma unroll
    for (int f = 0; f < 4; ++f) {
      bf16x8 bfr = *(const bf16x8*)&sB[(f * 16 + l15) * 40 + q8];
      acc[f] = __builtin_amdgcn_mfma_f32_16x16x32_bf16(af, bfr, acc[f], 0, 0, 0);
    }
    __syncthreads();
  }
  int r0 = m0 + wave * 16 + (lane >> 4) * 4;
#pragma unroll
  for (int f = 0; f < 4; ++f) {
    int col = n0 + f * 16 + l15;
    float bv = bias ? bias[col] : 0.f;
#pragma unroll
    for (int r = 0; r < 4; ++r)
      C[(size_t)(r0 + r) * 512 + col] = acc[f][r] + bv;
  }
}

// ---------------- post-fuse: x = gelu(LN1(y1)); t = bf16(LN2(x)) ----------------
__global__ __launch_bounds__(256) void k_post_y1(const float* __restrict__ y,
    float* __restrict__ x, u16* __restrict__ t,
    const float* __restrict__ g1, const float* __restrict__ b1,
    const float* __restrict__ g2, const float* __restrict__ b2) {
  __shared__ float sm[8];
  int row = blockIdx.x, tid = threadIdx.x;
  size_t base = (size_t)row * 512;
  float v0 = y[base + tid], v1 = y[base + tid + 256];
  float s = v0 + v1, ss = v0 * v0 + v1 * v1;
  bred2(s, ss, sm, tid);
  float m = s * (1.f / 512.f);
  float inv = rsqrtf(ss * (1.f / 512.f) - m * m + 1e-5f);
  float x0 = gelu((v0 - m) * inv * g1[tid] + b1[tid]);
  float x1 = gelu((v1 - m) * inv * g1[tid + 256] + b1[tid + 256]);
  x[base + tid] = x0; x[base + tid + 256] = x1;
  s = x0 + x1; ss = x0 * x0 + x1 * x1;
  bred2(s, ss, sm, tid);
  m = s * (1.f / 512.f);
  inv = rsqrtf(ss * (1.f / 512.f) - m * m + 1e-5f);
  t[base + tid] = f2bf((x0 - m) * inv * g2[tid] + b2[tid]);
  t[base + tid + 256] = f2bf((x1 - m) * inv * g2[tid + 256] + b2[tid + 256]);
}

// ---------------- residual post: x += 0.1*gelu(h); then LN2->t (or LN3->out) ----------------
__global__ __launch_bounds__(256) void k_post_res(const float* __restrict__ h,
    float* __restrict__ x, u16* __restrict__ t, float* __restrict__ out,
    const float* __restrict__ g, const float* __restrict__ bb, int final_) {
  __shared__ float sm[8];
  int row = blockIdx.x, tid = threadIdx.x;
  size_t base = (size_t)row * 512;
  float x0 = x[base + tid] + 0.1f * gelu(h[base + tid]);
  float x1 = x[base + tid + 256] + 0.1f * gelu(h[base + tid + 256]);
  float s = x0 + x1, ss = x0 * x0 + x1 * x1;
  bred2(s, ss, sm, tid);
  float m = s * (1.f / 512.f);
  float inv = rsqrtf(ss * (1.f / 512.f) - m * m + 1e-5f);
  float n0 = (x0 - m) * inv * g[tid] + bb[tid];
  float n1 = (x1 - m) * inv * g[tid + 256] + bb[tid + 256];
  if (final_) {
    out[base + tid] = n0; out[base + tid + 256] = n1;
  } else {
    x[base + tid] = x0; x[base + tid + 256] = x1;
    t[base + tid] = f2bf(n0); t[base + tid + 256] = f2bf(n1);
  }
}

// ---------------------------------------------------------------------------
extern "C" void kernel_launch(void* const* d_in, const int* in_sizes, int n_in,
                              void* d_out, int out_size, void* d_ws, size_t ws_size,
                              hipStream_t stream) {
  const float* emb     = (const float*)d_in[0];
  const int*   tok     = (const int*)d_in[1];
  const float* mask    = (const float*)d_in[2];
  const float* sim     = (const float*)d_in[3];
  const float* W_scale = (const float*)d_in[4];
  const float* b_scale = (const float*)d_in[5];
  const float* W_sem   = (const float*)d_in[6];
  const float* b_sem   = (const float*)d_in[7];
  const float* W_ctx   = (const float*)d_in[8];
  const float* b_ctx   = (const float*)d_in[9];
  const float* W_fuse  = (const float*)d_in[10];
  const float* b_fuse  = (const float*)d_in[11];
  const float* ln1_g = (const float*)d_in[12], *ln1_b = (const float*)d_in[13];
  const float* ln2_g = (const float*)d_in[14], *ln2_b = (const float*)d_in[15];
  const float* ln3_g = (const float*)d_in[16], *ln3_b = (const float*)d_in[17];
  const float* W_e0 = (const float*)d_in[18], *b_e0 = (const float*)d_in[19];
  const float* W_e1 = (const float*)d_in[20], *b_e1 = (const float*)d_in[21];
  const float* W_e2 = (const float*)d_in[22], *b_e2 = (const float*)d_in[23];
  float* out = (float*)d_out;

  char* w = (char*)d_ws; size_t off = 0;
  auto alloc = [&](size_t bytes) { void* p = w + off; off += (bytes + 255) & ~(size_t)255; return p; };
  float* phases = (float*)alloc((size_t)4096 * 512 * 4);
  float* hbuf   = (float*)alloc((size_t)4096 * 512 * 4);
  float* xbuf   = (float*)alloc((size_t)4096 * 512 * 4);
  u16*   tbuf   = (u16*)  alloc((size_t)4096 * 512 * 2);
  u16*   xcat   = (u16*)  alloc((size_t)4096 * KCAT * 2);
  u16*   wcatT  = (u16*)  alloc((size_t)512 * KCAT * 2);
  u16*   We0T   = (u16*)  alloc((size_t)512 * 512 * 2);
  u16*   We1T   = (u16*)  alloc((size_t)512 * 512 * 2);
  u16*   We2T   = (u16*)  alloc((size_t)512 * 512 * 2);
  float* msc    = (float*)alloc((size_t)4096 * 5 * 4);
  // zero-init cluster (contiguous, sizes all multiples of 256 B: one memset)
  float* semacc   = (float*)alloc((size_t)1024 * 4);
  float* cmacc    = (float*)alloc((size_t)4 * 512 * 4);
  float* dots_raw = (float*)alloc((size_t)4096 * 8 * 4);
  float* normsq   = (float*)alloc((size_t)4096 * 4);
  float* ctx_acc  = (float*)alloc((size_t)512 * 512 * 4);
  float* sm_acc   = (float*)alloc((size_t)7 * 512 * 4);
  (void)ws_size; (void)in_sizes; (void)n_in; (void)out_size;

  size_t zbytes = (size_t)(1024 + 4 * 512 + 4096 * 8 + 4096 + 512 * 512 + 7 * 512) * 4;
  hipMemsetAsync(semacc, 0, zbytes, stream);

  k_pre<<<1056, 256, 0, stream>>>(emb, mask, phases, cmacc);
  k_dots<<<dim3(64, 32), 256, 0, stream>>>(sim, tok, dots_raw, normsq);
  k_coh<<<1024, 256, 0, stream>>>(phases, dots_raw, normsq, msc, semacc);

  k_wbig<<<576, 256, 0, stream>>>(W_e0, W_e1, W_e2, W_fuse, W_ctx,
                                  W_scale, W_sem, b_scale, b_sem, b_ctx,
                                  We0T, We1T, We2T, wcatT, ctx_acc, sm_acc);
  k_packfin<<<66, 256, 0, stream>>>(ctx_acc, sm_acc, b_fuse, wcatT);

  k_xcat<<<4096, 256, 0, stream>>>(emb, cmacc, msc, semacc, xcat);
  k_gemm<<<dim3(64, 8), 256, 0, stream>>>(xcat, wcatT, hbuf, nullptr, KCAT);
  k_post_y1<<<4096, 256, 0, stream>>>(hbuf, xbuf, tbuf, ln1_g, ln1_b, ln2_g, ln2_b);

  k_gemm<<<dim3(64, 8), 256, 0, stream>>>(tbuf, We0T, hbuf, b_e0, 512);
  k_post_res<<<4096, 256, 0, stream>>>(hbuf, xbuf, tbuf, nullptr, ln2_g, ln2_b, 0);
  k_gemm<<<dim3(64, 8), 256, 0, stream>>>(tbuf, We1T, hbuf, b_e1, 512);
  k_post_res<<<4096, 256, 0, stream>>>(hbuf, xbuf, tbuf, nullptr, ln2_g, ln2_b, 0);
  k_gemm<<<dim3(64, 8), 256, 0, stream>>>(tbuf, We2T, hbuf, b_e2, 512);
  k_post_res<<<4096, 256, 0, stream>>>(hbuf, xbuf, nullptr, out, ln3_g, ln3_b, 1);
}

// Round 5
// 609.635 us; speedup vs baseline: 1.0760x; 1.0760x over previous
//
#include <hip/hip_runtime.h>

// ---------------------------------------------------------------------------
// HardwareOptimizedQuantumLLM  (B=4, S=1024, D=512, V=8192, SCALES={1,2,4,8,16}, WIN=8)
//
// R5: k_dots v3 (36 KB LDS -> 4 blocks/CU, float4 staging, CP=129 bank-perfect
// reads); k_coh v2 (LDS band staging, 45 KB, CP2=132 bank-perfect, quad-lane
// reduce). k_dots was latency/phase-bound at 2 blocks/CU (650 GB/s, occ 22%).
// ---------------------------------------------------------------------------

#define DEV __device__ __forceinline__
typedef unsigned short u16;
typedef __bf16 bf16x8 __attribute__((ext_vector_type(8)));
typedef float f32x4 __attribute__((ext_vector_type(4)));

static constexpr int S = 1024;
static constexpr int D = 512;
static constexpr int KCAT = 1056;   // 512 ctx + 512 lc + 5 msc + 1 sem + 1 const + 25 pad

DEV u16 f2bf(float f) {            // fp32 -> bf16 (RNE)
  unsigned u = __float_as_uint(f);
  return (u16)((u + 0x7fffu + ((u >> 16) & 1u)) >> 16);
}
DEV float gelu(float x) { return 0.5f * x * (1.f + erff(x * 0.70710678118654752f)); }
DEV float wred(float v) {
#pragma unroll
  for (int off = 32; off; off >>= 1) v += __shfl_down(v, off, 64);
  return v;
}
DEV void bred2(float& a, float& b, float* sm, int tid) {
  a = wred(a); b = wred(b);
  int w = tid >> 6;
  if ((tid & 63) == 0) { sm[w] = a; sm[w + 4] = b; }
  __syncthreads();
  a = sm[0] + sm[1] + sm[2] + sm[3];
  b = sm[4] + sm[5] + sm[6] + sm[7];
  __syncthreads();
}
DEV float qred(float v) {          // sum over quads (lanes x^1, x^2)
  v += __shfl_xor(v, 1, 64);
  v += __shfl_xor(v, 2, 64);
  return v;
}

// ---------------- pre: blocks 0..1023 tanh(emb); 1024..1055 cmean ----------------
__global__ __launch_bounds__(256) void k_pre(const float* __restrict__ emb,
                                             const float* __restrict__ mask,
                                             float* __restrict__ ph,
                                             float* __restrict__ cmacc) {
  int blk = blockIdx.x, tid = threadIdx.x;
  if (blk < 1024) {
    int idx = blk * 256 + tid;
#pragma unroll
    for (int r = 0; r < 2; ++r, idx += 262144) {
      float4 v = ((const float4*)emb)[idx];
      float4 o;
      o.x = tanhf(v.x); o.y = tanhf(v.y); o.z = tanhf(v.z); o.w = tanhf(v.w);
      ((float4*)ph)[idx] = o;
    }
  } else {
    int r = blk - 1024, b = r >> 3, chunk = r & 7;
    float a0 = 0.f, a1 = 0.f;
    for (int s = chunk * 128; s < chunk * 128 + 128; ++s) {
      float m = mask[b * S + s];
      const float* row = emb + (size_t)(b * S + s) * D;
      a0 += row[tid] * m; a1 += row[tid + 256] * m;
    }
    atomicAdd(cmacc + b * D + tid, a0);
    atomicAdd(cmacc + b * D + tid + 256, a1);
  }
}

// ---------------- banded tsim + norms v3 ----------------
// grid (64, 64): bx = (b,64-anchor group), by = 128-float V chunk.
// LDS sT[r][c]: 72 x 129 fp32 = 36.3 KB -> 4 blocks/CU. CP=129 (==1 mod 32):
// compute reads lane-stride 129 -> bank-perfect; one vaddr + imm offsets.
static constexpr int CP = 129;
__global__ __launch_bounds__(256) void k_dots(const float* __restrict__ sim,
                                              const int* __restrict__ tok,
                                              float* __restrict__ dots_raw,
                                              float* __restrict__ normsq) {
  __shared__ float sT[72 * CP];
  __shared__ int stok[72];
  int bx = blockIdx.x, cy = blockIdx.y, tid = threadIdx.x;
  int b = bx >> 4, g0 = (bx & 15) * 64, gidx = b * S + g0;
  if (tid < 72) {
    int p = g0 + tid;
    stok[tid] = (p < S) ? tok[b * S + p] : -1;
  }
  __syncthreads();
  const float4* sim4 = (const float4*)sim;
#pragma unroll
  for (int it = 0; it < 9; ++it) {          // 72 rows x 32 float4 = 9/thread
    int u = it * 256 + tid, r = u >> 5, q = u & 31;
    int tk = stok[r];
    float4 v = make_float4(0.f, 0.f, 0.f, 0.f);
    if (tk >= 0) v = sim4[(size_t)tk * 2048 + cy * 32 + q];
    float* dst = &sT[r * CP + 4 * q];
    dst[0] = v.x; dst[1] = v.y; dst[2] = v.z; dst[3] = v.w;
  }
  __syncthreads();
  int wave = tid >> 6, lane = tid & 63;
  float acc[9] = {};
  const float* base = &sT[lane * CP + wave * 32];
#pragma unroll 4
  for (int cc = 0; cc < 32; ++cc) {
    float va = base[cc];
    acc[8] += va * va;
#pragma unroll
    for (int o = 1; o <= 8; ++o) acc[o - 1] += va * base[o * CP + cc];
  }
  __syncthreads();
  float* red = sT;                           // reuse as [wave][9][64]
#pragma unroll
  for (int s = 0; s < 9; ++s) red[(wave * 9 + s) * 64 + lane] = acc[s];
  __syncthreads();
  for (int u = tid; u < 576; u += 256) {
    int s = u >> 6, a = u & 63;
    float v = red[s * 64 + a] + red[(9 + s) * 64 + a] +
              red[(18 + s) * 64 + a] + red[(27 + s) * 64 + a];
    if (s < 8) atomicAdd(&dots_raw[(size_t)(gidx + a) * 8 + s], v);
    else       atomicAdd(&normsq[gidx + a], v);
  }
}

// ---------------- fused msc + sem v2: LDS band staging ----------------
// grid (64, 4): bx = (b, 64-anchor group), by = 128-d chunk.
// LDS sP[r][d]: 88 x 132 fp32 = 45.4 KB. Lane = (anchor quad): ar=tid>>2,
// dq=tid&3, d = dq + 4*dd -> bank = (4*row + lane) mod 32: conflict-free.
static constexpr int CP2 = 132;
__global__ __launch_bounds__(256) void k_coh(const float* __restrict__ ph,
                                             const float* __restrict__ dots_raw,
                                             const float* __restrict__ normsq,
                                             float* __restrict__ msc_raw,
                                             float* __restrict__ semacc) {
  __shared__ float sP[88 * CP2];
  __shared__ float sw2[64 * 17];
  int bx = blockIdx.x, dy = blockIdx.y, tid = threadIdx.x;
  int b = bx >> 4, g0 = (bx & 15) * 64;
  const float4* ph4 = (const float4*)ph;
#pragma unroll
  for (int it = 0; it < 11; ++it) {          // 88 rows x 32 float4 = 11/thread
    int u = it * 256 + tid, r = u >> 5, q = u & 31;
    int gr = g0 - 8 + r;
    gr = gr < 0 ? 0 : (gr > S - 1 ? S - 1 : gr);
    float4 v = ph4[(size_t)(b * S + gr) * 128 + dy * 32 + q];
    *(float4*)&sP[r * CP2 + 4 * q] = v;      // 528r+16q bytes: 16B-aligned
  }
  for (int u = tid; u < 1088; u += 256) {    // swin table 64 anchors x 17
    int a = u / 17, oi = u - a * 17;
    int i = g0 + a, o = oi - 8, j = i + o;
    int idx = b * S + i;
    float v = 0.f;
    if (j >= 0 && j < S) {
      if (o == 0) v = 1.f;
      else {
        float dr = (o > 0) ? dots_raw[(size_t)idx * 8 + o - 1]
                           : dots_raw[(size_t)(idx + o) * 8 + (-o - 1)];
        float ni = fmaxf(sqrtf(normsq[idx]), 1e-12f);
        float nj = fmaxf(sqrtf(normsq[idx + o]), 1e-12f);
        v = dr / (ni * nj);
      }
    }
    sw2[u] = v;
  }
  __syncthreads();
  int ar = tid >> 2, dq = tid & 3;
  int i = g0 + ar, idx = b * S + i;
  int jmax = S - 1 - i; if (jmax > 15) jmax = 15;
  float swr[17];
#pragma unroll
  for (int oi = 0; oi < 17; ++oi) swr[oi] = sw2[ar * 17 + oi];  // fully-unrolled uses only
  float a0 = 0.f, a1 = 0.f, a2 = 0.f, a3 = 0.f, a4 = 0.f, asem = 0.f;
#pragma unroll 2
  for (int dd = 0; dd < 32; ++dd) {
    int d = dq + 4 * dd;
    const float* pb = &sP[(ar + 8) * CP2 + d];   // row i
    // --- msc prefix walk (rows i .. i+15) ---
    float sp = 0.f, sc = 0.f, ss = 0.f;
#pragma unroll
    for (int j = 0; j < 16; ++j) {
      float x = (j <= jmax) ? pb[j * CP2] : 0.f;
      sp += x; sc += __cosf(x); ss += __sinf(x);
      if (j == 0) a0 += __cosf(sp) * sc + __sinf(sp) * ss;
      else if (j == 1)  { float wm = sp * 0.5f;    a1 += __cosf(wm) * (sc * 0.5f)    + __sinf(wm) * (ss * 0.5f); }
      else if (j == 3)  { float wm = sp * 0.25f;   a2 += __cosf(wm) * (sc * 0.25f)   + __sinf(wm) * (ss * 0.25f); }
      else if (j == 7)  { float wm = sp * 0.125f;  a3 += __cosf(wm) * (sc * 0.125f)  + __sinf(wm) * (ss * 0.125f); }
      else if (j == 15) { float wm = sp * 0.0625f; a4 += __cosf(wm) * (sc * 0.0625f) + __sinf(wm) * (ss * 0.0625f); }
    }
    // --- sem +/-8 window (rows i-8 .. i+8) ---
    float p0 = pb[0];
    const float* qb = &sP[ar * CP2 + d];
#pragma unroll
    for (int oi = 0; oi < 17; ++oi) {
      int j = i + oi - 8;
      bool valid = (j >= 0) && (j < S);
      float pj = qb[oi * CP2];
      asem += valid ? __cosf((p0 - pj) * swr[oi]) : 0.f;
    }
  }
  a0 = qred(a0); a1 = qred(a1); a2 = qred(a2); a3 = qred(a3); a4 = qred(a4);
  asem = qred(asem);
  if (dq == 0) {
    float* mr = msc_raw + (size_t)idx * 5;
    atomicAdd(mr + 0, a0); atomicAdd(mr + 1, a1); atomicAdd(mr + 2, a2);
    atomicAdd(mr + 3, a3); atomicAdd(mr + 4, a4);
    atomicAdd(semacc + i, asem);
  }
}

// ---------------- weight stage A (block-switched): prep | wcf | wsmall ----------------
__global__ __launch_bounds__(256) void k_wbig(const float* __restrict__ W0,
    const float* __restrict__ W1, const float* __restrict__ W2,
    const float* __restrict__ Wf, const float* __restrict__ wctx,
    const float* __restrict__ Wsc, const float* __restrict__ Wsm,
    const float* __restrict__ bsc, const float* __restrict__ bsm,
    const float* __restrict__ bcx,
    u16* __restrict__ T0, u16* __restrict__ T1, u16* __restrict__ T2,
    u16* __restrict__ wcatT, float* __restrict__ ctx_acc,
    float* __restrict__ sm_acc) {
  __shared__ float tile[64][65];
  int blk = blockIdx.x, tid = threadIdx.x;
  if (blk < 256) {
    int z = blk >> 6, rem = blk & 63;
    const float* src = z == 0 ? W0 : z == 1 ? W1 : z == 2 ? W2 : Wf + (size_t)1536 * 512;
    int r0 = (rem >> 3) * 64, c0 = (rem & 7) * 64;
    int tr = tid >> 6, tc = tid & 63;
#pragma unroll 4
    for (int i = 0; i < 16; ++i)
      tile[tr + i * 4][tc] = src[(size_t)(r0 + tr + i * 4) * 512 + c0 + tc];
    __syncthreads();
#pragma unroll 4
    for (int i = 0; i < 16; ++i) {
      int n = c0 + tr + i * 4, k = r0 + tc;
      u16 v = f2bf(tile[tc][tr + i * 4]);
      if (z == 3) wcatT[(size_t)n * KCAT + 512 + k] = v;
      else (z == 0 ? T0 : z == 1 ? T1 : T2)[(size_t)n * 512 + k] = v;
    }
  } else if (blk < 512) {
    int rem = blk - 256;
    int n = (rem & 1) * 256 + tid;
    int kbase = ((rem & 63) >> 1) * 16;
    int j0 = (rem >> 6) * 128;
    float acc[16] = {};
    for (int j = j0; j < j0 + 128; ++j) {
      float wf3 = Wf[(size_t)(1024 + j) * 512 + n];
#pragma unroll
      for (int kk = 0; kk < 16; ++kk) acc[kk] += wctx[(size_t)(kbase + kk) * 512 + j] * wf3;
    }
#pragma unroll
    for (int kk = 0; kk < 16; ++kk)
      atomicAdd(&ctx_acc[(size_t)(kbase + kk) * 512 + n], acc[kk]);
  } else {
    int rem = blk - 512;
    int n = (rem & 1) * 256 + tid;
    int j0 = (rem >> 1) * 16;
    float a0 = 0.f, a1 = 0.f, a2 = 0.f, a3 = 0.f, a4 = 0.f, au = 0.f, ac = 0.f;
    for (int j = j0; j < j0 + 16; ++j) {
      float wf1 = Wf[(size_t)j * 512 + n];
      float wf2 = Wf[(size_t)(512 + j) * 512 + n];
      float wf3 = Wf[(size_t)(1024 + j) * 512 + n];
      a0 += Wsc[j] * wf1; a1 += Wsc[512 + j] * wf1; a2 += Wsc[1024 + j] * wf1;
      a3 += Wsc[1536 + j] * wf1; a4 += Wsc[2048 + j] * wf1;
      au += Wsm[j] * wf2;
      ac += bsc[j] * wf1 + bsm[j] * wf2 + bcx[j] * wf3;
    }
    atomicAdd(&sm_acc[0 * 512 + n], a0);
    atomicAdd(&sm_acc[1 * 512 + n], a1);
    atomicAdd(&sm_acc[2 * 512 + n], a2);
    atomicAdd(&sm_acc[3 * 512 + n], a3);
    atomicAdd(&sm_acc[4 * 512 + n], a4);
    atomicAdd(&sm_acc[5 * 512 + n], au);
    atomicAdd(&sm_acc[6 * 512 + n], ac);
  }
}

// ---------------- weight stage B: pack ctx_acc -> wcatT | finalize small cols ----
__global__ __launch_bounds__(256) void k_packfin(const float* __restrict__ ctx_acc,
    const float* __restrict__ sm_acc, const float* __restrict__ bfu,
    u16* __restrict__ wcatT) {
  __shared__ float tile[64][65];
  int blk = blockIdx.x, tid = threadIdx.x;
  if (blk < 64) {
    int r0 = (blk >> 3) * 64, c0 = (blk & 7) * 64;
    int tr = tid >> 6, tc = tid & 63;
#pragma unroll 4
    for (int i = 0; i < 16; ++i)
      tile[tr + i * 4][tc] = ctx_acc[(size_t)(r0 + tr + i * 4) * 512 + c0 + tc];
    __syncthreads();
#pragma unroll 4
    for (int i = 0; i < 16; ++i)
      wcatT[(size_t)(c0 + tr + i * 4) * KCAT + r0 + tc] = f2bf(tile[tc][tr + i * 4]);
  } else {
    int n = (blk - 64) * 256 + tid;
    u16* row = wcatT + (size_t)n * KCAT;
#pragma unroll
    for (int s = 0; s < 6; ++s) row[1024 + s] = f2bf(sm_acc[s * 512 + n]);
    row[1030] = f2bf(sm_acc[6 * 512 + n] + bfu[n]);
    for (int k = 1031; k < KCAT; ++k) row[k] = 0;
  }
}

// ---------------- build Xcat (bf16): [cos(emb-cmean) | lc | msc | sem | 1 | 0] ----------------
__global__ __launch_bounds__(256) void k_xcat(const float* __restrict__ emb,
    const float* __restrict__ cmacc, const float* __restrict__ msc_raw,
    const float* __restrict__ semacc, u16* __restrict__ xcat) {
  int idx = blockIdx.x, b = idx >> 10, i = idx & 1023, tid = threadIdx.x;
  const float* erow = emb + (size_t)idx * D;
  u16* orow = xcat + (size_t)idx * KCAT;
  for (int c = tid; c < KCAT; c += 256) {
    float v;
    if (c < 512) {
      v = __cosf(erow[c] - cmacc[b * D + c] * (1.f / 1024.f));
    } else if (c < 1024) {
      int d = c - 512;
      v = (i < S - 1) ? __cosf(erow[D + d] - erow[d]) : 0.f;
    } else if (c < 1029) {
      int s = c - 1024, req = (1 << s) - 1;    // scale s valid iff jmax >= 2^s-1
      v = (S - 1 - i >= req) ? msc_raw[(size_t)idx * 5 + s] * (1.f / 512.f) : 0.f;
    } else if (c == 1029) {
      int cnt = ((i < 8) ? i : 8) + ((S - 1 - i < 8) ? (S - 1 - i) : 8) + 1;
      v = semacc[i] / (4.f * (float)cnt * 512.f);
    } else if (c == 1030) {
      v = 1.f;
    } else v = 0.f;
    orow[c] = f2bf(v);
  }
}

// ---------------- bf16 MFMA GEMM: C[M,512] = A[M,K] @ BT[512,K]^T + bias ----------------
__global__ __launch_bounds__(256) void k_gemm(const u16* __restrict__ A,
    const u16* __restrict__ BT, float* __restrict__ C,
    const float* __restrict__ bias, int K) {
  __shared__ __align__(16) u16 sA[64 * 40];
  __shared__ __align__(16) u16 sB[64 * 40];
  int tid = threadIdx.x, wave = tid >> 6, lane = tid & 63;
  int m0 = blockIdx.x * 64, n0 = blockIdx.y * 64;
  int lr = tid >> 2, lc = (tid & 3) * 8;
  int q8 = (lane >> 4) * 8, l15 = lane & 15;
  const u16* Ap = A + (size_t)(m0 + lr) * K + lc;
  const u16* Bp = BT + (size_t)(n0 + lr) * K + lc;
  f32x4 acc[4] = {};
  for (int k0 = 0; k0 < K; k0 += 32) {
    *(uint4*)&sA[lr * 40 + lc] = *(const uint4*)(Ap + k0);
    *(uint4*)&sB[lr * 40 + lc] = *(const uint4*)(Bp + k0);
    __syncthreads();
    bf16x8 af = *(const bf16x8*)&sA[(wave * 16 + l15) * 40 + q8];
#pragma unroll
    for (int f = 0; f < 4; ++f) {
      bf16x8 bfr = *(const bf16x8*)&sB[(f * 16 + l15) * 40 + q8];
      acc[f] = __builtin_amdgcn_mfma_f32_16x16x32_bf16(af, bfr, acc[f], 0, 0, 0);
    }
    __syncthreads();
  }
  int r0 = m0 + wave * 16 + (lane >> 4) * 4;
#pragma unroll
  for (int f = 0; f < 4; ++f) {
    int col = n0 + f * 16 + l15;
    float bv = bias ? bias[col] : 0.f;
#pragma unroll
    for (int r = 0; r < 4; ++r)
      C[(size_t)(r0 + r) * 512 + col] = acc[f][r] + bv;
  }
}

// ---------------- post-fuse: x = gelu(LN1(y1)); t = bf16(LN2(x)) ----------------
__global__ __launch_bounds__(256) void k_post_y1(const float* __restrict__ y,
    float* __restrict__ x, u16* __restrict__ t,
    const float* __restrict__ g1, const float* __restrict__ b1,
    const float* __restrict__ g2, const float* __restrict__ b2) {
  __shared__ float sm[8];
  int row = blockIdx.x, tid = threadIdx.x;
  size_t base = (size_t)row * 512;
  float v0 = y[base + tid], v1 = y[base + tid + 256];
  float s = v0 + v1, ss = v0 * v0 + v1 * v1;
  bred2(s, ss, sm, tid);
  float m = s * (1.f / 512.f);
  float inv = rsqrtf(ss * (1.f / 512.f) - m * m + 1e-5f);
  float x0 = gelu((v0 - m) * inv * g1[tid] + b1[tid]);
  float x1 = gelu((v1 - m) * inv * g1[tid + 256] + b1[tid + 256]);
  x[base + tid] = x0; x[base + tid + 256] = x1;
  s = x0 + x1; ss = x0 * x0 + x1 * x1;
  bred2(s, ss, sm, tid);
  m = s * (1.f / 512.f);
  inv = rsqrtf(ss * (1.f / 512.f) - m * m + 1e-5f);
  t[base + tid] = f2bf((x0 - m) * inv * g2[tid] + b2[tid]);
  t[base + tid + 256] = f2bf((x1 - m) * inv * g2[tid + 256] + b2[tid + 256]);
}

// ---------------- residual post: x += 0.1*gelu(h); then LN2->t (or LN3->out) ----------------
__global__ __launch_bounds__(256) void k_post_res(const float* __restrict__ h,
    float* __restrict__ x, u16* __restrict__ t, float* __restrict__ out,
    const float* __restrict__ g, const float* __restrict__ bb, int final_) {
  __shared__ float sm[8];
  int row = blockIdx.x, tid = threadIdx.x;
  size_t base = (size_t)row * 512;
  float x0 = x[base + tid] + 0.1f * gelu(h[base + tid]);
  float x1 = x[base + tid + 256] + 0.1f * gelu(h[base + tid + 256]);
  float s = x0 + x1, ss = x0 * x0 + x1 * x1;
  bred2(s, ss, sm, tid);
  float m = s * (1.f / 512.f);
  float inv = rsqrtf(ss * (1.f / 512.f) - m * m + 1e-5f);
  float n0 = (x0 - m) * inv * g[tid] + bb[tid];
  float n1 = (x1 - m) * inv * g[tid + 256] + bb[tid + 256];
  if (final_) {
    out[base + tid] = n0; out[base + tid + 256] = n1;
  } else {
    x[base + tid] = x0; x[base + tid + 256] = x1;
    t[base + tid] = f2bf(n0); t[base + tid + 256] = f2bf(n1);
  }
}

// ---------------------------------------------------------------------------
extern "C" void kernel_launch(void* const* d_in, const int* in_sizes, int n_in,
                              void* d_out, int out_size, void* d_ws, size_t ws_size,
                              hipStream_t stream) {
  const float* emb     = (const float*)d_in[0];
  const int*   tok     = (const int*)d_in[1];
  const float* mask    = (const float*)d_in[2];
  const float* sim     = (const float*)d_in[3];
  const float* W_scale = (const float*)d_in[4];
  const float* b_scale = (const float*)d_in[5];
  const float* W_sem   = (const float*)d_in[6];
  const float* b_sem   = (const float*)d_in[7];
  const float* W_ctx   = (const float*)d_in[8];
  const float* b_ctx   = (const float*)d_in[9];
  const float* W_fuse  = (const float*)d_in[10];
  const float* b_fuse  = (const float*)d_in[11];
  const float* ln1_g = (const float*)d_in[12], *ln1_b = (const float*)d_in[13];
  const float* ln2_g = (const float*)d_in[14], *ln2_b = (const float*)d_in[15];
  const float* ln3_g = (const float*)d_in[16], *ln3_b = (const float*)d_in[17];
  const float* W_e0 = (const float*)d_in[18], *b_e0 = (const float*)d_in[19];
  const float* W_e1 = (const float*)d_in[20], *b_e1 = (const float*)d_in[21];
  const float* W_e2 = (const float*)d_in[22], *b_e2 = (const float*)d_in[23];
  float* out = (float*)d_out;

  char* w = (char*)d_ws; size_t off = 0;
  auto alloc = [&](size_t bytes) { void* p = w + off; off += (bytes + 255) & ~(size_t)255; return p; };
  float* phases = (float*)alloc((size_t)4096 * 512 * 4);
  float* hbuf   = (float*)alloc((size_t)4096 * 512 * 4);
  float* xbuf   = (float*)alloc((size_t)4096 * 512 * 4);
  u16*   tbuf   = (u16*)  alloc((size_t)4096 * 512 * 2);
  u16*   xcat   = (u16*)  alloc((size_t)4096 * KCAT * 2);
  u16*   wcatT  = (u16*)  alloc((size_t)512 * KCAT * 2);
  u16*   We0T   = (u16*)  alloc((size_t)512 * 512 * 2);
  u16*   We1T   = (u16*)  alloc((size_t)512 * 512 * 2);
  u16*   We2T   = (u16*)  alloc((size_t)512 * 512 * 2);
  // zero-init cluster (contiguous, sizes multiples of 256 B: one memset)
  float* semacc   = (float*)alloc((size_t)1024 * 4);
  float* cmacc    = (float*)alloc((size_t)4 * 512 * 4);
  float* dots_raw = (float*)alloc((size_t)4096 * 8 * 4);
  float* normsq   = (float*)alloc((size_t)4096 * 4);
  float* msc_raw  = (float*)alloc((size_t)4096 * 5 * 4);
  float* ctx_acc  = (float*)alloc((size_t)512 * 512 * 4);
  float* sm_acc   = (float*)alloc((size_t)7 * 512 * 4);
  (void)ws_size; (void)in_sizes; (void)n_in; (void)out_size;

  size_t zbytes = (size_t)(1024 + 4 * 512 + 4096 * 8 + 4096 + 4096 * 5 + 512 * 512 + 7 * 512) * 4;
  hipMemsetAsync(semacc, 0, zbytes, stream);

  k_pre<<<1056, 256, 0, stream>>>(emb, mask, phases, cmacc);
  k_dots<<<dim3(64, 64), 256, 0, stream>>>(sim, tok, dots_raw, normsq);
  k_coh<<<dim3(64, 4), 256, 0, stream>>>(phases, dots_raw, normsq, msc_raw, semacc);

  k_wbig<<<576, 256, 0, stream>>>(W_e0, W_e1, W_e2, W_fuse, W_ctx,
                                  W_scale, W_sem, b_scale, b_sem, b_ctx,
                                  We0T, We1T, We2T, wcatT, ctx_acc, sm_acc);
  k_packfin<<<66, 256, 0, stream>>>(ctx_acc, sm_acc, b_fuse, wcatT);

  k_xcat<<<4096, 256, 0, stream>>>(emb, cmacc, msc_raw, semacc, xcat);
  k_gemm<<<dim3(64, 8), 256, 0, stream>>>(xcat, wcatT, hbuf, nullptr, KCAT);
  k_post_y1<<<4096, 256, 0, stream>>>(hbuf, xbuf, tbuf, ln1_g, ln1_b, ln2_g, ln2_b);

  k_gemm<<<dim3(64, 8), 256, 0, stream>>>(tbuf, We0T, hbuf, b_e0, 512);
  k_post_res<<<4096, 256, 0, stream>>>(hbuf, xbuf, tbuf, nullptr, ln2_g, ln2_b, 0);
  k_gemm<<<dim3(64, 8), 256, 0, stream>>>(tbuf, We1T, hbuf, b_e1, 512);
  k_post_res<<<4096, 256, 0, stream>>>(hbuf, xbuf, tbuf, nullptr, ln2_g, ln2_b, 0);
  k_gemm<<<dim3(64, 8), 256, 0, stream>>>(tbuf, We2T, hbuf, b_e2, 512);
  k_post_res<<<4096, 256, 0, stream>>>(hbuf, xbuf, nullptr, out, ln3_g, ln3_b, 1);
}